// Round 2
// baseline (31520.728 us; speedup 1.0000x reference)
//
#include <hip/hip_runtime.h>
#include <cstdint>
#include <cstddef>

// Problem constants (LSTM_66726611911224)
#define TT   2048
#define BB   64
#define IND  128
#define HH   256
#define GG   1024   // 4*H, gate order i,f,g,o
#define OUTD 128
#define TC   128    // time-chunk size
#define NCH  (TT / TC)

// ---- workspace layout (bytes), total ~20.9 MB ----
static const size_t XG_OFF     = 0;                         // f16 [TC*B][1024] = 16,777,216
static const size_t HST_OFF    = 16777216ull;               // f16 [TC*B][256]  =  4,194,304
static const size_t WHH_OFF    = HST_OFF  + 4194304ull;     // uint4 [32][1024] =    524,288
static const size_t WIH_OFF    = WHH_OFF  + 524288ull;      // uint4 [16384]    =    262,144
static const size_t WOUT_OFF   = WIH_OFF  + 262144ull;      // f16 [128][256]   =     65,536
static const size_t BSUM_OFF   = WOUT_OFF + 65536ull;       // f32 [1024]       =      4,096
static const size_t HSTATE_OFF = BSUM_OFF + 4096ull;        // f16 [64][256]    =     32,768
static const size_t CSTATE_OFF = HSTATE_OFF + 32768ull;     // f32 [64][256]    =     65,536
static const size_t WS_NEEDED  = CSTATE_OFF + 65536ull;     // = 21,925,888

typedef _Float16 h2 __attribute__((ext_vector_type(2)));

union U16 { uint4 u; h2 h[4]; };          // 16B <-> 4x half2
union HU  { unsigned short u; _Float16 h; };

__device__ __forceinline__ float fdot2f(h2 a, h2 b, float c) {
#if __has_builtin(__builtin_amdgcn_fdot2)
  return __builtin_amdgcn_fdot2(a, b, c, false);   // v_dot2_f32_f16, f32 accumulate
#else
  return c + (float)a.x * (float)b.x + (float)a.y * (float)b.y;
#endif
}

__device__ __forceinline__ float sigm(float x) { return 1.f / (1.f + __expf(-x)); }
__device__ __forceinline__ float tanh_fast(float x) {
  float ax = fabsf(x);
  float e  = __expf(-2.f * ax);          // in (0,1], no overflow
  float r  = (1.f - e) / (1.f + e);
  return x < 0.f ? -r : r;
}

// ---------------- K0: pack weights to f16 layouts, bias sum ----------------
__global__ void k0_pack(const float* __restrict__ Whh, const float* __restrict__ Wih,
                        const float* __restrict__ Wout, const float* __restrict__ bih,
                        const float* __restrict__ bhh, uint8_t* __restrict__ ws) {
  int tid = blockIdx.x * 256 + threadIdx.x;
  if (tid < 32768) {                       // W_hh -> [k8][g] packed f16
    int k8 = tid >> 10, g = tid & 1023;
    const float4* s = (const float4*)(Whh + (size_t)g * HH + k8 * 8);
    float4 v0 = s[0], v1 = s[1];
    U16 o;
    o.h[0].x = (_Float16)v0.x; o.h[0].y = (_Float16)v0.y;
    o.h[1].x = (_Float16)v0.z; o.h[1].y = (_Float16)v0.w;
    o.h[2].x = (_Float16)v1.x; o.h[2].y = (_Float16)v1.y;
    o.h[3].x = (_Float16)v1.z; o.h[3].y = (_Float16)v1.w;
    ((uint4*)(ws + WHH_OFF))[tid] = o.u;   // index = k8*1024 + g
  } else if (tid < 65536) {                // W_out -> f16, row-major [128][256]
    int t2 = tid - 32768;
    ((_Float16*)(ws + WOUT_OFF))[t2] = (_Float16)Wout[t2];
  } else if (tid < 81920) {                // W_ih -> f16, row-major [1024][128], 8-packed
    int i = tid - 65536;
    const float4* s = (const float4*)(Wih + (size_t)i * 8);
    float4 v0 = s[0], v1 = s[1];
    U16 o;
    o.h[0].x = (_Float16)v0.x; o.h[0].y = (_Float16)v0.y;
    o.h[1].x = (_Float16)v0.z; o.h[1].y = (_Float16)v0.w;
    o.h[2].x = (_Float16)v1.x; o.h[2].y = (_Float16)v1.y;
    o.h[3].x = (_Float16)v1.z; o.h[3].y = (_Float16)v1.w;
    ((uint4*)(ws + WIH_OFF))[i] = o.u;
  } else if (tid < 82944) {                // bias sum
    int n = tid - 81920;
    ((float*)(ws + BSUM_OFF))[n] = bih[n] + bhh[n];
  }
}

// ---------------- K1: xg chunk = x @ W_ih^T + (b_ih+b_hh), f16 out ----------------
// One thread per row m (local, chunk has TC*B=8192 rows); x row in 64 half2 regs.
__global__ void __launch_bounds__(256) k1_xgemm(const float* __restrict__ x,
                                                uint8_t* __restrict__ ws, int t0) {
  const uint4* Wp   = (const uint4*)(ws + WIH_OFF);
  const float* bsum = (const float*)(ws + BSUM_OFF);
  _Float16*    xg   = (_Float16*)(ws + XG_OFF);

  int m = blockIdx.x * 256 + threadIdx.x;            // < TC*BB = 8192
  const float4* xr = (const float4*)(x + ((size_t)t0 * BB + m) * IND);
  h2 xv[64];
  #pragma unroll
  for (int i = 0; i < 32; ++i) {
    float4 v = xr[i];
    xv[2*i  ].x = (_Float16)v.x; xv[2*i  ].y = (_Float16)v.y;
    xv[2*i+1].x = (_Float16)v.z; xv[2*i+1].y = (_Float16)v.w;
  }
  _Float16* xgrow = xg + (size_t)m * GG;
  for (int n8 = 0; n8 < 128; ++n8) {
    float acc[8];
    #pragma unroll
    for (int j = 0; j < 8; ++j) {
      int row = n8 * 8 + j;                          // wave-uniform
      const uint4* wr = Wp + (size_t)row * 16;
      float a = bsum[row];
      #pragma unroll
      for (int q = 0; q < 16; ++q) {
        U16 w; w.u = wr[q];
        a = fdot2f(w.h[0], xv[4*q+0], a);
        a = fdot2f(w.h[1], xv[4*q+1], a);
        a = fdot2f(w.h[2], xv[4*q+2], a);
        a = fdot2f(w.h[3], xv[4*q+3], a);
      }
      acc[j] = a;
    }
    U16 o;
    #pragma unroll
    for (int p = 0; p < 4; ++p) { o.h[p].x = (_Float16)acc[2*p]; o.h[p].y = (_Float16)acc[2*p+1]; }
    *(uint4*)(xgrow + n8 * 8) = o.u;
  }
}

// ---------------- K2: recurrence chunk, 1 wg per batch element ----------------
// 512 threads: thread computes gates g0=tid (i/f) and g1=tid+512 (g/o).
// h (f16) in LDS, c in registers of threads 0..255; state persisted in ws.
__global__ void __launch_bounds__(512) k2_recur(uint8_t* __restrict__ ws,
                                                float* __restrict__ out, int t0) {
  const int tid = threadIdx.x;
  const int b   = blockIdx.x;
  const uint4* Wp = (const uint4*)(ws + WHH_OFF);
  const unsigned short* xp = (const unsigned short*)(ws + XG_OFF);
  _Float16* hst    = (_Float16*)(ws + HST_OFF);
  _Float16* hstate = (_Float16*)(ws + HSTATE_OFF);
  float*    cstate = (float*)(ws + CSTATE_OFF);

  __shared__ alignas(16) _Float16 h_h[HH];
  __shared__ float ga[512];
  __shared__ float gb[512];

  if (tid < 32) {
    ((uint4*)h_h)[tid] = (t0 == 0) ? make_uint4(0u, 0u, 0u, 0u)
                                   : ((const uint4*)(hstate + (size_t)b * HH))[tid];
  }
  float c = 0.f;
  if (tid < 256 && t0 != 0) c = cstate[(size_t)b * HH + tid];
  __syncthreads();

  const uint4* wp0 = Wp + tid;                   // column g0 of [k8][g]
  size_t xloc = (size_t)b * GG + tid;            // local chunk row offset
  HU r0, r1;
  r0.u = xp[xloc]; r1.u = xp[xloc + 512];        // prefetch first step

  for (int tt = 0; tt < TC; ++tt) {
    const int t = t0 + tt;
    float a0 = (float)r0.h;
    float a1 = (float)r1.h;
    if (tt + 1 < TC) {                           // prefetch next step's xg
      size_t nb = xloc + (size_t)(tt + 1) * (BB * GG);
      r0.u = xp[nb]; r1.u = xp[nb + 512];
    }
    const uint4* hv = (const uint4*)h_h;
    #pragma unroll 8
    for (int k8 = 0; k8 < 32; ++k8) {
      U16 w0; w0.u = wp0[(size_t)k8 * GG];       // coalesced: lanes = consecutive g
      U16 w1; w1.u = wp0[(size_t)k8 * GG + 512];
      U16 hh; hh.u = hv[k8];                     // wave-uniform LDS broadcast
      a0 = fdot2f(w0.h[0], hh.h[0], a0);
      a0 = fdot2f(w0.h[1], hh.h[1], a0);
      a0 = fdot2f(w0.h[2], hh.h[2], a0);
      a0 = fdot2f(w0.h[3], hh.h[3], a0);
      a1 = fdot2f(w1.h[0], hh.h[0], a1);
      a1 = fdot2f(w1.h[1], hh.h[1], a1);
      a1 = fdot2f(w1.h[2], hh.h[2], a1);
      a1 = fdot2f(w1.h[3], hh.h[3], a1);
    }
    ga[tid] = sigm(a0);                          // i (tid<256) or f (tid>=256)
    gb[tid] = (tid < 256) ? tanh_fast(a1) : sigm(a1);  // g or o
    __syncthreads();                             // gates visible; h reads done
    if (tid < 256) {
      float iv = ga[tid], fv = ga[tid + 256], gv = gb[tid], ov = gb[tid + 256];
      c = fv * c + iv * gv;
      float hn = ov * tanh_fast(c);
      h_h[tid] = (_Float16)hn;
      hst[((size_t)tt * BB + b) * HH + tid] = (_Float16)hn;
      if (t == TT - 1) {
        size_t tail = (size_t)TT * BB * OUTD;
        out[tail + (size_t)b * HH + tid] = hn;                       // h_T
        out[tail + (size_t)BB * HH + (size_t)b * HH + tid] = c;      // c_T
      }
    }
    __syncthreads();                             // new h visible
  }

  // persist state for next chunk
  if (tid < 32) ((uint4*)(hstate + (size_t)b * HH))[tid] = ((const uint4*)h_h)[tid];
  if (tid < 256) cstate[(size_t)b * HH + tid] = c;
}

// ---------------- K3: y chunk = h_hist @ W_out^T + b_out, f32 out ----------------
__global__ void __launch_bounds__(256) k3_out(uint8_t* __restrict__ ws,
                                              const float* __restrict__ b_out,
                                              float* __restrict__ out, int t0) {
  const uint4* Wp = (const uint4*)(ws + WOUT_OFF);   // [128][32] uint4
  const _Float16* hst = (const _Float16*)(ws + HST_OFF);
  int m = blockIdx.x * 256 + threadIdx.x;            // < TC*BB = 8192
  const uint4* xr = (const uint4*)(hst + (size_t)m * HH);
  h2 xv[128];
  #pragma unroll
  for (int i = 0; i < 32; ++i) {
    U16 w; w.u = xr[i];
    xv[4*i+0] = w.h[0]; xv[4*i+1] = w.h[1]; xv[4*i+2] = w.h[2]; xv[4*i+3] = w.h[3];
  }
  float* orow = out + ((size_t)t0 * BB + m) * OUTD;
  for (int n8 = 0; n8 < 16; ++n8) {
    float acc[8];
    #pragma unroll
    for (int j = 0; j < 8; ++j) {
      int row = n8 * 8 + j;                          // wave-uniform
      const uint4* wr = Wp + (size_t)row * 32;
      float a = b_out[row];
      #pragma unroll
      for (int q = 0; q < 32; ++q) {
        U16 w; w.u = wr[q];
        a = fdot2f(w.h[0], xv[4*q+0], a);
        a = fdot2f(w.h[1], xv[4*q+1], a);
        a = fdot2f(w.h[2], xv[4*q+2], a);
        a = fdot2f(w.h[3], xv[4*q+3], a);
      }
      acc[j] = a;
    }
    float4 o0 = make_float4(acc[0], acc[1], acc[2], acc[3]);
    float4 o1 = make_float4(acc[4], acc[5], acc[6], acc[7]);
    *(float4*)(orow + n8 * 8)     = o0;
    *(float4*)(orow + n8 * 8 + 4) = o1;
  }
}

extern "C" void kernel_launch(void* const* d_in, const int* in_sizes, int n_in,
                              void* d_out, int out_size, void* d_ws, size_t ws_size,
                              hipStream_t stream) {
  const float* input = (const float*)d_in[0];
  const float* W_ih  = (const float*)d_in[1];
  const float* W_hh  = (const float*)d_in[2];
  const float* b_ih  = (const float*)d_in[3];
  const float* b_hh  = (const float*)d_in[4];
  const float* W_out = (const float*)d_in[5];
  const float* b_out = (const float*)d_in[6];
  float*   out = (float*)d_out;
  uint8_t* ws  = (uint8_t*)d_ws;

  if (ws_size < WS_NEEDED) return;   // fail validation cleanly instead of faulting

  hipLaunchKernelGGL(k0_pack, dim3(324), dim3(256), 0, stream,
                     W_hh, W_ih, W_out, b_ih, b_hh, ws);
  for (int ch = 0; ch < NCH; ++ch) {
    const int t0 = ch * TC;
    hipLaunchKernelGGL(k1_xgemm, dim3(32), dim3(256), 0, stream, input, ws, t0);
    hipLaunchKernelGGL(k2_recur, dim3(64), dim3(512), 0, stream, ws, out, t0);
    hipLaunchKernelGGL(k3_out,   dim3(32), dim3(256), 0, stream, ws, b_out, out, t0);
  }
}

// Round 3
// 9879.779 us; speedup vs baseline: 3.1904x; 3.1904x over previous
//
#include <hip/hip_runtime.h>
#include <cstdint>
#include <cstddef>

// Problem constants (LSTM_66726611911224)
#define TT   2048
#define BB   64
#define IND  128
#define HH   256
#define GG   1024   // 4*H, gate order i,f,g,o
#define OUTD 128
#define TC   128    // time-chunk size
#define NCH  (TT / TC)

// ---- workspace layout (bytes), total ~20.9 MB ----
static const size_t XG_OFF     = 0;                         // f16 [TC*B][1024] = 16,777,216
static const size_t HST_OFF    = 16777216ull;               // f16 [TC*B][256]  =  4,194,304
static const size_t WHH_OFF    = HST_OFF  + 4194304ull;     // uint4 [32][1024] =    524,288
static const size_t WIH_OFF    = WHH_OFF  + 524288ull;      // uint4 [16384]    =    262,144
static const size_t WOUT_OFF   = WIH_OFF  + 262144ull;      // f16 [128][256]   =     65,536
static const size_t BSUM_OFF   = WOUT_OFF + 65536ull;       // f32 [1024]       =      4,096
static const size_t HSTATE_OFF = BSUM_OFF + 4096ull;        // f16 [64][256]    =     32,768
static const size_t CSTATE_OFF = HSTATE_OFF + 32768ull;     // f32 [64][256]    =     65,536
static const size_t WS_NEEDED  = CSTATE_OFF + 65536ull;     // = 21,925,888

typedef _Float16 h2 __attribute__((ext_vector_type(2)));

union U16 { uint4 u; h2 h[4]; };          // 16B <-> 4x half2
union HU  { unsigned short u; _Float16 h; };

__device__ __forceinline__ float fdot2f(h2 a, h2 b, float c) {
#if __has_builtin(__builtin_amdgcn_fdot2)
  return __builtin_amdgcn_fdot2(a, b, c, false);   // v_dot2_f32_f16, f32 accumulate
#else
  return c + (float)a.x * (float)b.x + (float)a.y * (float)b.y;
#endif
}

__device__ __forceinline__ float sigm(float x) { return 1.f / (1.f + __expf(-x)); }
__device__ __forceinline__ float tanh_fast(float x) {
  float ax = fabsf(x);
  float e  = __expf(-2.f * ax);          // in (0,1], no overflow
  float r  = (1.f - e) / (1.f + e);
  return x < 0.f ? -r : r;
}

// ---------------- K0: pack weights to f16 layouts, bias sum ----------------
__global__ void k0_pack(const float* __restrict__ Whh, const float* __restrict__ Wih,
                        const float* __restrict__ Wout, const float* __restrict__ bih,
                        const float* __restrict__ bhh, uint8_t* __restrict__ ws) {
  int tid = blockIdx.x * 256 + threadIdx.x;
  if (tid < 32768) {                       // W_hh -> [k8][g] packed f16
    int k8 = tid >> 10, g = tid & 1023;
    const float4* s = (const float4*)(Whh + (size_t)g * HH + k8 * 8);
    float4 v0 = s[0], v1 = s[1];
    U16 o;
    o.h[0].x = (_Float16)v0.x; o.h[0].y = (_Float16)v0.y;
    o.h[1].x = (_Float16)v0.z; o.h[1].y = (_Float16)v0.w;
    o.h[2].x = (_Float16)v1.x; o.h[2].y = (_Float16)v1.y;
    o.h[3].x = (_Float16)v1.z; o.h[3].y = (_Float16)v1.w;
    ((uint4*)(ws + WHH_OFF))[tid] = o.u;   // index = k8*1024 + g
  } else if (tid < 65536) {                // W_out -> f16, row-major [128][256]
    int t2 = tid - 32768;
    ((_Float16*)(ws + WOUT_OFF))[t2] = (_Float16)Wout[t2];
  } else if (tid < 81920) {                // W_ih -> f16, row-major [1024][128], 8-packed
    int i = tid - 65536;
    const float4* s = (const float4*)(Wih + (size_t)i * 8);
    float4 v0 = s[0], v1 = s[1];
    U16 o;
    o.h[0].x = (_Float16)v0.x; o.h[0].y = (_Float16)v0.y;
    o.h[1].x = (_Float16)v0.z; o.h[1].y = (_Float16)v0.w;
    o.h[2].x = (_Float16)v1.x; o.h[2].y = (_Float16)v1.y;
    o.h[3].x = (_Float16)v1.z; o.h[3].y = (_Float16)v1.w;
    ((uint4*)(ws + WIH_OFF))[i] = o.u;
  } else if (tid < 82944) {                // bias sum
    int n = tid - 81920;
    ((float*)(ws + BSUM_OFF))[n] = bih[n] + bhh[n];
  }
}

// ---------------- K1: xg chunk = x @ W_ih^T + (b_ih+b_hh), f16 out ----------------
// Grid 512 = 16 col-segments x 32 row-blocks. Block stages its 64 W rows in LDS
// (16 KB, broadcast ds_read); thread holds its x row in 64 h2 regs, computes 64 cols.
__global__ void __launch_bounds__(256) k1_xgemm(const float* __restrict__ x,
                                                uint8_t* __restrict__ ws, int t0) {
  const uint4* Wp   = (const uint4*)(ws + WIH_OFF);
  const float* bsum = (const float*)(ws + BSUM_OFF);
  _Float16*    xg   = (_Float16*)(ws + XG_OFF);

  const int s = blockIdx.x >> 5;                       // col segment (64 cols)
  const int m = ((blockIdx.x & 31) << 8) + threadIdx.x;

  __shared__ uint4 wlds[1024];                         // 64 rows x 16 uint4
  __shared__ float bsl[64];
  #pragma unroll
  for (int i = 0; i < 4; ++i)
    wlds[i * 256 + threadIdx.x] = Wp[(size_t)(s << 6) * 16 + i * 256 + threadIdx.x];
  if (threadIdx.x < 64) bsl[threadIdx.x] = bsum[(s << 6) + threadIdx.x];
  __syncthreads();

  const float4* xr = (const float4*)(x + ((size_t)t0 * BB + m) * IND);
  h2 xv[64];
  #pragma unroll
  for (int i = 0; i < 32; ++i) {
    float4 v = xr[i];
    xv[2*i  ].x = (_Float16)v.x; xv[2*i  ].y = (_Float16)v.y;
    xv[2*i+1].x = (_Float16)v.z; xv[2*i+1].y = (_Float16)v.w;
  }
  _Float16* xgrow = xg + (size_t)m * GG + (s << 6);
  for (int g = 0; g < 8; ++g) {
    float acc[8];
    #pragma unroll
    for (int j = 0; j < 8; ++j) {
      const uint4* wr = &wlds[(g * 8 + j) * 16];
      float a = bsl[g * 8 + j];
      #pragma unroll
      for (int q = 0; q < 16; ++q) {
        U16 w; w.u = wr[q];
        a = fdot2f(w.h[0], xv[4*q+0], a);
        a = fdot2f(w.h[1], xv[4*q+1], a);
        a = fdot2f(w.h[2], xv[4*q+2], a);
        a = fdot2f(w.h[3], xv[4*q+3], a);
      }
      acc[j] = a;
    }
    U16 o;
    #pragma unroll
    for (int p = 0; p < 4; ++p) { o.h[p].x = (_Float16)acc[2*p]; o.h[p].y = (_Float16)acc[2*p+1]; }
    *(uint4*)(xgrow + g * 8) = o.u;
  }
}

// ---------------- K2: recurrence chunk, 1 wg per batch element ----------------
// 512 threads: thread computes gates g0=tid (i/f) and g1=tid+512 (g/o).
// h (f16) in LDS, c in registers of threads 0..255; state persisted in ws.
__global__ void __launch_bounds__(512) k2_recur(uint8_t* __restrict__ ws,
                                                float* __restrict__ out, int t0) {
  const int tid = threadIdx.x;
  const int b   = blockIdx.x;
  const uint4* Wp = (const uint4*)(ws + WHH_OFF);
  const unsigned short* xp = (const unsigned short*)(ws + XG_OFF);
  _Float16* hst    = (_Float16*)(ws + HST_OFF);
  _Float16* hstate = (_Float16*)(ws + HSTATE_OFF);
  float*    cstate = (float*)(ws + CSTATE_OFF);

  __shared__ alignas(16) _Float16 h_h[HH];
  __shared__ float ga[512];
  __shared__ float gb[512];

  if (tid < 32) {
    ((uint4*)h_h)[tid] = (t0 == 0) ? make_uint4(0u, 0u, 0u, 0u)
                                   : ((const uint4*)(hstate + (size_t)b * HH))[tid];
  }
  float c = 0.f;
  if (tid < 256 && t0 != 0) c = cstate[(size_t)b * HH + tid];
  __syncthreads();

  const uint4* wp0 = Wp + tid;                   // column g0 of [k8][g]
  size_t xloc = (size_t)b * GG + tid;            // local chunk row offset
  HU r0, r1;
  r0.u = xp[xloc]; r1.u = xp[xloc + 512];        // prefetch first step

  for (int tt = 0; tt < TC; ++tt) {
    const int t = t0 + tt;
    float a0 = (float)r0.h;
    float a1 = (float)r1.h;
    if (tt + 1 < TC) {                           // prefetch next step's xg
      size_t nb = xloc + (size_t)(tt + 1) * (BB * GG);
      r0.u = xp[nb]; r1.u = xp[nb + 512];
    }
    const uint4* hv = (const uint4*)h_h;
    #pragma unroll 8
    for (int k8 = 0; k8 < 32; ++k8) {
      U16 w0; w0.u = wp0[(size_t)k8 * GG];       // coalesced: lanes = consecutive g
      U16 w1; w1.u = wp0[(size_t)k8 * GG + 512];
      U16 hh; hh.u = hv[k8];                     // wave-uniform LDS broadcast
      a0 = fdot2f(w0.h[0], hh.h[0], a0);
      a0 = fdot2f(w0.h[1], hh.h[1], a0);
      a0 = fdot2f(w0.h[2], hh.h[2], a0);
      a0 = fdot2f(w0.h[3], hh.h[3], a0);
      a1 = fdot2f(w1.h[0], hh.h[0], a1);
      a1 = fdot2f(w1.h[1], hh.h[1], a1);
      a1 = fdot2f(w1.h[2], hh.h[2], a1);
      a1 = fdot2f(w1.h[3], hh.h[3], a1);
    }
    ga[tid] = sigm(a0);                          // i (tid<256) or f (tid>=256)
    gb[tid] = (tid < 256) ? tanh_fast(a1) : sigm(a1);  // g or o
    __syncthreads();                             // gates visible; h reads done
    if (tid < 256) {
      float iv = ga[tid], fv = ga[tid + 256], gv = gb[tid], ov = gb[tid + 256];
      c = fv * c + iv * gv;
      float hn = ov * tanh_fast(c);
      h_h[tid] = (_Float16)hn;
      hst[((size_t)tt * BB + b) * HH + tid] = (_Float16)hn;
      if (t == TT - 1) {
        size_t tail = (size_t)TT * BB * OUTD;
        out[tail + (size_t)b * HH + tid] = hn;                       // h_T
        out[tail + (size_t)BB * HH + (size_t)b * HH + tid] = c;      // c_T
      }
    }
    __syncthreads();                             // new h visible
  }

  // persist state for next chunk
  if (tid < 32) ((uint4*)(hstate + (size_t)b * HH))[tid] = ((const uint4*)h_h)[tid];
  if (tid < 256) cstate[(size_t)b * HH + tid] = c;
}

// ---------------- K3: y chunk = h_hist @ W_out^T + b_out, f32 out ----------------
// Grid 512 = 16 col-segments x 32 row-blocks. Block stages 8 W_out rows (4 KB) in
// LDS; thread streams its h row (32 uint4) against 8 accumulators.
__global__ void __launch_bounds__(256) k3_out(uint8_t* __restrict__ ws,
                                              const float* __restrict__ b_out,
                                              float* __restrict__ out, int t0) {
  const uint4* Wp = (const uint4*)(ws + WOUT_OFF);   // [128][32] uint4
  const _Float16* hst = (const _Float16*)(ws + HST_OFF);
  const int s = blockIdx.x >> 5;                     // col segment (8 cols)
  const int m = ((blockIdx.x & 31) << 8) + threadIdx.x;

  __shared__ uint4 wlds[256];                        // 8 rows x 32 uint4
  __shared__ float bsl[8];
  wlds[threadIdx.x] = Wp[((size_t)s << 3) * 32 + threadIdx.x];
  if (threadIdx.x < 8) bsl[threadIdx.x] = b_out[(s << 3) + threadIdx.x];
  __syncthreads();

  const uint4* xr = (const uint4*)(hst + (size_t)m * HH);
  float acc[8];
  #pragma unroll
  for (int j = 0; j < 8; ++j) acc[j] = bsl[j];
  #pragma unroll 4
  for (int q = 0; q < 32; ++q) {
    U16 hhv; hhv.u = xr[q];
    #pragma unroll
    for (int j = 0; j < 8; ++j) {
      U16 w; w.u = wlds[j * 32 + q];
      acc[j] = fdot2f(w.h[0], hhv.h[0], acc[j]);
      acc[j] = fdot2f(w.h[1], hhv.h[1], acc[j]);
      acc[j] = fdot2f(w.h[2], hhv.h[2], acc[j]);
      acc[j] = fdot2f(w.h[3], hhv.h[3], acc[j]);
    }
  }
  float* orow = out + ((size_t)t0 * BB + m) * OUTD + (s << 3);
  *(float4*)(orow)     = make_float4(acc[0], acc[1], acc[2], acc[3]);
  *(float4*)(orow + 4) = make_float4(acc[4], acc[5], acc[6], acc[7]);
}

extern "C" void kernel_launch(void* const* d_in, const int* in_sizes, int n_in,
                              void* d_out, int out_size, void* d_ws, size_t ws_size,
                              hipStream_t stream) {
  const float* input = (const float*)d_in[0];
  const float* W_ih  = (const float*)d_in[1];
  const float* W_hh  = (const float*)d_in[2];
  const float* b_ih  = (const float*)d_in[3];
  const float* b_hh  = (const float*)d_in[4];
  const float* W_out = (const float*)d_in[5];
  const float* b_out = (const float*)d_in[6];
  float*   out = (float*)d_out;
  uint8_t* ws  = (uint8_t*)d_ws;

  if (ws_size < WS_NEEDED) return;   // fail validation cleanly instead of faulting

  hipLaunchKernelGGL(k0_pack, dim3(324), dim3(256), 0, stream,
                     W_hh, W_ih, W_out, b_ih, b_hh, ws);
  for (int ch = 0; ch < NCH; ++ch) {
    const int t0 = ch * TC;
    hipLaunchKernelGGL(k1_xgemm, dim3(512), dim3(256), 0, stream, input, ws, t0);
    hipLaunchKernelGGL(k2_recur, dim3(64),  dim3(512), 0, stream, ws, out, t0);
    hipLaunchKernelGGL(k3_out,   dim3(512), dim3(256), 0, stream, ws, b_out, out, t0);
  }
}

// Round 4
// 7884.996 us; speedup vs baseline: 3.9976x; 1.2530x over previous
//
#include <hip/hip_runtime.h>
#include <cstdint>
#include <cstddef>

// Problem constants (LSTM_66726611911224)
#define TT   2048
#define BB   64
#define IND  128
#define HH   256
#define GG   1024   // 4*H, gate order i,f,g,o
#define OUTD 128
#define TC   128    // time-chunk size
#define NCH  (TT / TC)

// ---- workspace layout (bytes), total ~20.9 MB ----
static const size_t XG_OFF     = 0;                         // f16 [TC*B][1024] = 16,777,216
static const size_t HST_OFF    = 16777216ull;               // f16 [TC*B][256]  =  4,194,304
static const size_t WHH_OFF    = HST_OFF  + 4194304ull;     // uint4 [4][2][16][256] = 524,288
static const size_t WIH_OFF    = WHH_OFF  + 524288ull;      // uint4 [16384]    =    262,144
static const size_t WOUT_OFF   = WIH_OFF  + 262144ull;      // f16 [128][256]   =     65,536
static const size_t BSUM_OFF   = WOUT_OFF + 65536ull;       // f32 [1024]       =      4,096
static const size_t HSTATE_OFF = BSUM_OFF + 4096ull;        // f16 [64][256]    =     32,768
static const size_t CSTATE_OFF = HSTATE_OFF + 32768ull;     // f32 [64][256]    =     65,536
static const size_t WS_NEEDED  = CSTATE_OFF + 65536ull;     // = 21,925,888

typedef _Float16 h2 __attribute__((ext_vector_type(2)));

union U16 { uint4 u; h2 h[4]; };          // 16B <-> 4x half2
union HU  { unsigned short u; _Float16 h; };

__device__ __forceinline__ float fdot2f(h2 a, h2 b, float c) {
#if __has_builtin(__builtin_amdgcn_fdot2)
  return __builtin_amdgcn_fdot2(a, b, c, false);   // v_dot2_f32_f16, f32 accumulate
#else
  return c + (float)a.x * (float)b.x + (float)a.y * (float)b.y;
#endif
}

__device__ __forceinline__ float sigm(float x) { return 1.f / (1.f + __expf(-x)); }
__device__ __forceinline__ float tanh_fast(float x) {
  float ax = fabsf(x);
  float e  = __expf(-2.f * ax);          // in (0,1], no overflow
  float r  = (1.f - e) / (1.f + e);
  return x < 0.f ? -r : r;
}

// ---------------- K0: pack weights to f16 layouts, bias sum ----------------
// W_hh layout for k2: uint4 index = rr*8192 + half*4096 + q*256 + u
//   rr 0/1/2 -> rows u / 256+u / 768+u (i,f,o; reg-resident in k2)
//   rr 3     -> row 512+u (g; LDS/stream in k2)
//   k-range of the uint4: half*128 + q*8 .. +8
__global__ void k0_pack(const float* __restrict__ Whh, const float* __restrict__ Wih,
                        const float* __restrict__ Wout, const float* __restrict__ bih,
                        const float* __restrict__ bhh, uint8_t* __restrict__ ws) {
  int tid = blockIdx.x * 256 + threadIdx.x;
  if (tid < 32768) {
    int rr = tid >> 13, rem = tid & 8191;
    int hf = rem >> 12, q = (rem >> 8) & 15, u = rem & 255;
    int row = (rr == 0) ? u : (rr == 1) ? 256 + u : (rr == 2) ? 768 + u : 512 + u;
    int kb = hf * 128 + q * 8;
    const float4* s = (const float4*)(Whh + (size_t)row * HH + kb);
    float4 v0 = s[0], v1 = s[1];
    U16 o;
    o.h[0].x = (_Float16)v0.x; o.h[0].y = (_Float16)v0.y;
    o.h[1].x = (_Float16)v0.z; o.h[1].y = (_Float16)v0.w;
    o.h[2].x = (_Float16)v1.x; o.h[2].y = (_Float16)v1.y;
    o.h[3].x = (_Float16)v1.z; o.h[3].y = (_Float16)v1.w;
    ((uint4*)(ws + WHH_OFF))[tid] = o.u;
  } else if (tid < 65536) {                // W_out -> f16, row-major [128][256]
    int t2 = tid - 32768;
    ((_Float16*)(ws + WOUT_OFF))[t2] = (_Float16)Wout[t2];
  } else if (tid < 81920) {                // W_ih -> f16, row-major [1024][128], 8-packed
    int i = tid - 65536;
    const float4* s = (const float4*)(Wih + (size_t)i * 8);
    float4 v0 = s[0], v1 = s[1];
    U16 o;
    o.h[0].x = (_Float16)v0.x; o.h[0].y = (_Float16)v0.y;
    o.h[1].x = (_Float16)v0.z; o.h[1].y = (_Float16)v0.w;
    o.h[2].x = (_Float16)v1.x; o.h[2].y = (_Float16)v1.y;
    o.h[3].x = (_Float16)v1.z; o.h[3].y = (_Float16)v1.w;
    ((uint4*)(ws + WIH_OFF))[i] = o.u;
  } else if (tid < 82944) {                // bias sum
    int n = tid - 81920;
    ((float*)(ws + BSUM_OFF))[n] = bih[n] + bhh[n];
  }
}

// ---------------- K1: xg chunk = x @ W_ih^T + (b_ih+b_hh), f16 out ----------------
__global__ void __launch_bounds__(256) k1_xgemm(const float* __restrict__ x,
                                                uint8_t* __restrict__ ws, int t0) {
  const uint4* Wp   = (const uint4*)(ws + WIH_OFF);
  const float* bsum = (const float*)(ws + BSUM_OFF);
  _Float16*    xg   = (_Float16*)(ws + XG_OFF);

  const int s = blockIdx.x >> 5;                       // col segment (64 cols)
  const int m = ((blockIdx.x & 31) << 8) + threadIdx.x;

  __shared__ uint4 wlds[1024];                         // 64 rows x 16 uint4
  __shared__ float bsl[64];
  #pragma unroll
  for (int i = 0; i < 4; ++i)
    wlds[i * 256 + threadIdx.x] = Wp[(size_t)(s << 6) * 16 + i * 256 + threadIdx.x];
  if (threadIdx.x < 64) bsl[threadIdx.x] = bsum[(s << 6) + threadIdx.x];
  __syncthreads();

  const float4* xr = (const float4*)(x + ((size_t)t0 * BB + m) * IND);
  h2 xv[64];
  #pragma unroll
  for (int i = 0; i < 32; ++i) {
    float4 v = xr[i];
    xv[2*i  ].x = (_Float16)v.x; xv[2*i  ].y = (_Float16)v.y;
    xv[2*i+1].x = (_Float16)v.z; xv[2*i+1].y = (_Float16)v.w;
  }
  _Float16* xgrow = xg + (size_t)m * GG + (s << 6);
  for (int g = 0; g < 8; ++g) {
    float acc[8];
    #pragma unroll
    for (int j = 0; j < 8; ++j) {
      const uint4* wr = &wlds[(g * 8 + j) * 16];
      float a = bsl[g * 8 + j];
      #pragma unroll
      for (int q = 0; q < 16; ++q) {
        U16 w; w.u = wr[q];
        a = fdot2f(w.h[0], xv[4*q+0], a);
        a = fdot2f(w.h[1], xv[4*q+1], a);
        a = fdot2f(w.h[2], xv[4*q+2], a);
        a = fdot2f(w.h[3], xv[4*q+3], a);
      }
      acc[j] = a;
    }
    U16 o;
    #pragma unroll
    for (int p = 0; p < 4; ++p) { o.h[p].x = (_Float16)acc[2*p]; o.h[p].y = (_Float16)acc[2*p+1]; }
    *(uint4*)(xgrow + g * 8) = o.u;
  }
}

// ---------------- K2: recurrence chunk, W_hh held on-chip ----------------
// 512 threads / wg, 1 wg per batch element. u=tid&255, half=tid>>8.
// Thread computes partial dots (its 128-k half) for gates {u, u+256, u+512, u+768}.
// i,f,o half-rows: 192 VGPRs. g half-row: LDS for tid<192 (48 KB), L2 stream else.
// half=1 posts partials to LDS; half=0 finishes gates, owns c, writes h.
__global__ void __launch_bounds__(512) k2_recur(uint8_t* __restrict__ ws,
                                                float* __restrict__ out, int t0) {
  const int tid  = threadIdx.x;
  const int b    = blockIdx.x;
  const int u    = tid & 255;
  const int half = tid >> 8;

  const uint4* WR = (const uint4*)(ws + WHH_OFF);     // rr<3: reg-resident rows
  const uint4* WG = WR + 24576;                       // rr=3: g rows [2][16][256]
  const unsigned short* xp = (const unsigned short*)(ws + XG_OFF);
  _Float16* hst    = (_Float16*)(ws + HST_OFF);
  _Float16* hstate = (_Float16*)(ws + HSTATE_OFF);
  float*    cstate = (float*)(ws + CSTATE_OFF);

  __shared__ uint4 gw[192 * 16];                      // 48 KB swizzled g-rows
  __shared__ alignas(16) _Float16 h_lds[HH];          // 512 B
  __shared__ float p_i[256], p_f[256], p_g[256], p_o[256];  // 4 KB partials

  // ---- one-time: load reg-resident W halves (i,f,o) ----
  h2 wi[64], wf[64], wo[64];
  #pragma unroll
  for (int q = 0; q < 16; ++q) {
    U16 a;
    a.u = WR[(size_t)((0 * 2 + half) * 16 + q) * 256 + u];
    wi[4*q+0]=a.h[0]; wi[4*q+1]=a.h[1]; wi[4*q+2]=a.h[2]; wi[4*q+3]=a.h[3];
    a.u = WR[(size_t)((1 * 2 + half) * 16 + q) * 256 + u];
    wf[4*q+0]=a.h[0]; wf[4*q+1]=a.h[1]; wf[4*q+2]=a.h[2]; wf[4*q+3]=a.h[3];
    a.u = WR[(size_t)((2 * 2 + half) * 16 + q) * 256 + u];
    wo[4*q+0]=a.h[0]; wo[4*q+1]=a.h[1]; wo[4*q+2]=a.h[2]; wo[4*q+3]=a.h[3];
  }
  const uint4* wgp = WG + (size_t)(half * 16) * 256 + u;   // + q*256 per q
  if (tid < 192) {
    #pragma unroll
    for (int q = 0; q < 16; ++q)
      gw[tid * 16 + (q ^ (tid & 15))] = wgp[(size_t)q * 256];
  }

  if (tid < 32) {
    uint4 z = make_uint4(0u, 0u, 0u, 0u);
    ((uint4*)h_lds)[tid] = (t0 == 0) ? z : ((const uint4*)(hstate + (size_t)b * HH))[tid];
  }
  float c = 0.f;
  if (half == 0 && t0 != 0) c = cstate[(size_t)b * HH + u];

  const size_t xrow = (size_t)b * GG;
  HU xi, xf, xgv, xo;
  if (half == 0) {
    xi.u  = xp[xrow + u];
    xf.u  = xp[xrow + 256 + u];
    xgv.u = xp[xrow + 512 + u];
    xo.u  = xp[xrow + 768 + u];
  }
  __syncthreads();

  for (int tt = 0; tt < TC; ++tt) {
    float ai = 0.f, af = 0.f, ag = 0.f, ao = 0.f;
    const uint4* hv = ((const uint4*)h_lds) + half * 16;
    if (tid < 192) {                                   // g from LDS (waves 0-2)
      #pragma unroll
      for (int q = 0; q < 16; ++q) {
        U16 hh; hh.u = hv[q];
        U16 wg_; wg_.u = gw[tid * 16 + (q ^ (tid & 15))];
        #pragma unroll
        for (int j = 0; j < 4; ++j) {
          ai = fdot2f(wi[4*q+j], hh.h[j], ai);
          af = fdot2f(wf[4*q+j], hh.h[j], af);
          ag = fdot2f(wg_.h[j],  hh.h[j], ag);
          ao = fdot2f(wo[4*q+j], hh.h[j], ao);
        }
      }
    } else {                                           // g streamed from L2 (waves 3-7)
      #pragma unroll
      for (int q = 0; q < 16; ++q) {
        U16 hh; hh.u = hv[q];
        U16 wg_; wg_.u = wgp[(size_t)q * 256];
        #pragma unroll
        for (int j = 0; j < 4; ++j) {
          ai = fdot2f(wi[4*q+j], hh.h[j], ai);
          af = fdot2f(wf[4*q+j], hh.h[j], af);
          ag = fdot2f(wg_.h[j],  hh.h[j], ag);
          ao = fdot2f(wo[4*q+j], hh.h[j], ao);
        }
      }
    }
    if (half == 1) { p_i[u] = ai; p_f[u] = af; p_g[u] = ag; p_o[u] = ao; }
    __syncthreads();                                   // partials visible; h reads done
    if (half == 0) {
      float gi = sigm(ai + p_i[u] + (float)xi.h);
      float gf = sigm(af + p_f[u] + (float)xf.h);
      float gg = tanh_fast(ag + p_g[u] + (float)xgv.h);
      float go = sigm(ao + p_o[u] + (float)xo.h);
      c = gf * c + gi * gg;
      float hn = go * tanh_fast(c);
      h_lds[u] = (_Float16)hn;
      hst[((size_t)tt * BB + b) * HH + u] = (_Float16)hn;
      if (tt + 1 < TC) {
        const size_t nx = xrow + (size_t)(tt + 1) * (BB * GG);
        xi.u  = xp[nx + u];
        xf.u  = xp[nx + 256 + u];
        xgv.u = xp[nx + 512 + u];
        xo.u  = xp[nx + 768 + u];
      }
      if (t0 + tt == TT - 1) {
        const size_t tail = (size_t)TT * BB * OUTD;
        out[tail + (size_t)b * HH + u] = hn;                       // h_T
        out[tail + (size_t)BB * HH + (size_t)b * HH + u] = c;      // c_T
      }
    }
    __syncthreads();                                   // new h visible
  }

  if (tid < 32) ((uint4*)(hstate + (size_t)b * HH))[tid] = ((const uint4*)h_lds)[tid];
  if (half == 0) cstate[(size_t)b * HH + u] = c;
}

// ---------------- K3: y chunk = h_hist @ W_out^T + b_out, f32 out ----------------
__global__ void __launch_bounds__(256) k3_out(uint8_t* __restrict__ ws,
                                              const float* __restrict__ b_out,
                                              float* __restrict__ out, int t0) {
  const uint4* Wp = (const uint4*)(ws + WOUT_OFF);   // [128][32] uint4
  const _Float16* hst = (const _Float16*)(ws + HST_OFF);
  const int s = blockIdx.x >> 5;                     // col segment (8 cols)
  const int m = ((blockIdx.x & 31) << 8) + threadIdx.x;

  __shared__ uint4 wlds[256];                        // 8 rows x 32 uint4
  __shared__ float bsl[8];
  wlds[threadIdx.x] = Wp[((size_t)s << 3) * 32 + threadIdx.x];
  if (threadIdx.x < 8) bsl[threadIdx.x] = b_out[(s << 3) + threadIdx.x];
  __syncthreads();

  const uint4* xr = (const uint4*)(hst + (size_t)m * HH);
  float acc[8];
  #pragma unroll
  for (int j = 0; j < 8; ++j) acc[j] = bsl[j];
  #pragma unroll 4
  for (int q = 0; q < 32; ++q) {
    U16 hhv; hhv.u = xr[q];
    #pragma unroll
    for (int j = 0; j < 8; ++j) {
      U16 w; w.u = wlds[j * 32 + q];
      acc[j] = fdot2f(w.h[0], hhv.h[0], acc[j]);
      acc[j] = fdot2f(w.h[1], hhv.h[1], acc[j]);
      acc[j] = fdot2f(w.h[2], hhv.h[2], acc[j]);
      acc[j] = fdot2f(w.h[3], hhv.h[3], acc[j]);
    }
  }
  float* orow = out + ((size_t)t0 * BB + m) * OUTD + (s << 3);
  *(float4*)(orow)     = make_float4(acc[0], acc[1], acc[2], acc[3]);
  *(float4*)(orow + 4) = make_float4(acc[4], acc[5], acc[6], acc[7]);
}

extern "C" void kernel_launch(void* const* d_in, const int* in_sizes, int n_in,
                              void* d_out, int out_size, void* d_ws, size_t ws_size,
                              hipStream_t stream) {
  const float* input = (const float*)d_in[0];
  const float* W_ih  = (const float*)d_in[1];
  const float* W_hh  = (const float*)d_in[2];
  const float* b_ih  = (const float*)d_in[3];
  const float* b_hh  = (const float*)d_in[4];
  const float* W_out = (const float*)d_in[5];
  const float* b_out = (const float*)d_in[6];
  float*   out = (float*)d_out;
  uint8_t* ws  = (uint8_t*)d_ws;

  if (ws_size < WS_NEEDED) return;   // fail validation cleanly instead of faulting

  hipLaunchKernelGGL(k0_pack, dim3(324), dim3(256), 0, stream,
                     W_hh, W_ih, W_out, b_ih, b_hh, ws);
  for (int ch = 0; ch < NCH; ++ch) {
    const int t0 = ch * TC;
    hipLaunchKernelGGL(k1_xgemm, dim3(512), dim3(256), 0, stream, input, ws, t0);
    hipLaunchKernelGGL(k2_recur, dim3(64),  dim3(512), 0, stream, ws, out, t0);
    hipLaunchKernelGGL(k3_out,   dim3(512), dim3(256), 0, stream, ws, b_out, out, t0);
  }
}

// Round 5
// 4569.349 us; speedup vs baseline: 6.8983x; 1.7256x over previous
//
#include <hip/hip_runtime.h>
#include <cstdint>
#include <cstddef>

// Problem constants (LSTM_66726611911224)
#define TT   2048
#define BB   64
#define IND  128
#define HH   256
#define GG   1024   // 4*H, gate order i,f,g,o
#define OUTD 128
#define TC   128    // time-chunk size
#define NCH  (TT / TC)

// ---- workspace layout (bytes), total ~20.9 MB ----
static const size_t XG_OFF     = 0;                         // f16 [TC*B][1024] = 16,777,216
static const size_t HST_OFF    = 16777216ull;               // f16 [TC*B][256]  =  4,194,304
static const size_t WHH_OFF    = HST_OFF  + 4194304ull;     // uint4 [4][2][16][256] = 524,288
static const size_t WIH_OFF    = WHH_OFF  + 524288ull;      // uint4 [16384]    =    262,144
static const size_t WOUT_OFF   = WIH_OFF  + 262144ull;      // f16 [128][256]   =     65,536
static const size_t BSUM_OFF   = WOUT_OFF + 65536ull;       // f32 [1024]       =      4,096
static const size_t HSTATE_OFF = BSUM_OFF + 4096ull;        // f16 [64][256]    =     32,768
static const size_t CSTATE_OFF = HSTATE_OFF + 32768ull;     // f32 [64][256]    =     65,536
static const size_t WS_NEEDED  = CSTATE_OFF + 65536ull;     // = 21,925,888

// k2 dynamic LDS layout
static const int GW_BYTES   = 512 * 16 * 16;                // 131072
static const int K2_LDS_SZ  = GW_BYTES + 512 + 4 * 1024;    // 135,680 B

typedef _Float16 h2 __attribute__((ext_vector_type(2)));

union U16 { uint4 u; h2 h[4]; };          // 16B <-> 4x half2
union HU  { unsigned short u; _Float16 h; };

__device__ __forceinline__ float fdot2f(h2 a, h2 b, float c) {
#if __has_builtin(__builtin_amdgcn_fdot2)
  return __builtin_amdgcn_fdot2(a, b, c, false);   // v_dot2_f32_f16, f32 accumulate
#else
  return c + (float)a.x * (float)b.x + (float)a.y * (float)b.y;
#endif
}

__device__ __forceinline__ float sigm(float x) { return 1.f / (1.f + __expf(-x)); }
__device__ __forceinline__ float tanh_fast(float x) {
  float ax = fabsf(x);
  float e  = __expf(-2.f * ax);          // in (0,1], no overflow
  float r  = (1.f - e) / (1.f + e);
  return x < 0.f ? -r : r;
}

// ---------------- K0: pack weights to f16 layouts, bias sum ----------------
// W_hh layout for k2: uint4 index = rr*8192 + half*4096 + q*256 + u
//   rr 0/1/2 -> rows u / 256+u / 768+u (i,f,o; reg-resident in k2)
//   rr 3     -> row 512+u (g; LDS-resident in k2)
//   k-range of the uint4: half*128 + q*8 .. +8
__global__ void k0_pack(const float* __restrict__ Whh, const float* __restrict__ Wih,
                        const float* __restrict__ Wout, const float* __restrict__ bih,
                        const float* __restrict__ bhh, uint8_t* __restrict__ ws) {
  int tid = blockIdx.x * 256 + threadIdx.x;
  if (tid < 32768) {
    int rr = tid >> 13, rem = tid & 8191;
    int hf = rem >> 12, q = (rem >> 8) & 15, u = rem & 255;
    int row = (rr == 0) ? u : (rr == 1) ? 256 + u : (rr == 2) ? 768 + u : 512 + u;
    int kb = hf * 128 + q * 8;
    const float4* s = (const float4*)(Whh + (size_t)row * HH + kb);
    float4 v0 = s[0], v1 = s[1];
    U16 o;
    o.h[0].x = (_Float16)v0.x; o.h[0].y = (_Float16)v0.y;
    o.h[1].x = (_Float16)v0.z; o.h[1].y = (_Float16)v0.w;
    o.h[2].x = (_Float16)v1.x; o.h[2].y = (_Float16)v1.y;
    o.h[3].x = (_Float16)v1.z; o.h[3].y = (_Float16)v1.w;
    ((uint4*)(ws + WHH_OFF))[tid] = o.u;
  } else if (tid < 65536) {                // W_out -> f16, row-major [128][256]
    int t2 = tid - 32768;
    ((_Float16*)(ws + WOUT_OFF))[t2] = (_Float16)Wout[t2];
  } else if (tid < 81920) {                // W_ih -> f16, row-major [1024][128], 8-packed
    int i = tid - 65536;
    const float4* s = (const float4*)(Wih + (size_t)i * 8);
    float4 v0 = s[0], v1 = s[1];
    U16 o;
    o.h[0].x = (_Float16)v0.x; o.h[0].y = (_Float16)v0.y;
    o.h[1].x = (_Float16)v0.z; o.h[1].y = (_Float16)v0.w;
    o.h[2].x = (_Float16)v1.x; o.h[2].y = (_Float16)v1.y;
    o.h[3].x = (_Float16)v1.z; o.h[3].y = (_Float16)v1.w;
    ((uint4*)(ws + WIH_OFF))[i] = o.u;
  } else if (tid < 82944) {                // bias sum
    int n = tid - 81920;
    ((float*)(ws + BSUM_OFF))[n] = bih[n] + bhh[n];
  }
}

// ---------------- K1: xg chunk = x @ W_ih^T + (b_ih+b_hh), f16 out ----------------
__global__ void __launch_bounds__(256) k1_xgemm(const float* __restrict__ x,
                                                uint8_t* __restrict__ ws, int t0) {
  const uint4* Wp   = (const uint4*)(ws + WIH_OFF);
  const float* bsum = (const float*)(ws + BSUM_OFF);
  _Float16*    xg   = (_Float16*)(ws + XG_OFF);

  const int s = blockIdx.x >> 5;                       // col segment (64 cols)
  const int m = ((blockIdx.x & 31) << 8) + threadIdx.x;

  __shared__ uint4 wlds[1024];                         // 64 rows x 16 uint4
  __shared__ float bsl[64];
  #pragma unroll
  for (int i = 0; i < 4; ++i)
    wlds[i * 256 + threadIdx.x] = Wp[(size_t)(s << 6) * 16 + i * 256 + threadIdx.x];
  if (threadIdx.x < 64) bsl[threadIdx.x] = bsum[(s << 6) + threadIdx.x];
  __syncthreads();

  const float4* xr = (const float4*)(x + ((size_t)t0 * BB + m) * IND);
  h2 xv[64];
  #pragma unroll
  for (int i = 0; i < 32; ++i) {
    float4 v = xr[i];
    xv[2*i  ].x = (_Float16)v.x; xv[2*i  ].y = (_Float16)v.y;
    xv[2*i+1].x = (_Float16)v.z; xv[2*i+1].y = (_Float16)v.w;
  }
  _Float16* xgrow = xg + (size_t)m * GG + (s << 6);
  for (int g = 0; g < 8; ++g) {
    float acc[8];
    #pragma unroll
    for (int j = 0; j < 8; ++j) {
      const uint4* wr = &wlds[(g * 8 + j) * 16];
      float a = bsl[g * 8 + j];
      #pragma unroll
      for (int q = 0; q < 16; ++q) {
        U16 w; w.u = wr[q];
        a = fdot2f(w.h[0], xv[4*q+0], a);
        a = fdot2f(w.h[1], xv[4*q+1], a);
        a = fdot2f(w.h[2], xv[4*q+2], a);
        a = fdot2f(w.h[3], xv[4*q+3], a);
      }
      acc[j] = a;
    }
    U16 o;
    #pragma unroll
    for (int p = 0; p < 4; ++p) { o.h[p].x = (_Float16)acc[2*p]; o.h[p].y = (_Float16)acc[2*p+1]; }
    *(uint4*)(xgrow + g * 8) = o.u;
  }
}

// ---------------- K2: recurrence chunk, W_hh fully on-chip ----------------
// 512 threads / wg, 1 wg per batch element. u=tid&255, half=tid>>8.
// Thread computes partial dots (its 128-k half) for gates {u, u+256, u+512, u+768}.
// i,f,o half-rows: 192 VGPRs (launch_bounds(512,2) -> 256-VGPR cap, no spill).
// g half-rows: 128 KB dynamic LDS, XOR-swizzled. Zero per-step global traffic
// except 4 xg scalars + 1 h-store per unit.
__global__ void __launch_bounds__(512, 2) k2_recur(uint8_t* __restrict__ ws,
                                                   float* __restrict__ out, int t0) {
  const int tid  = threadIdx.x;
  const int b    = blockIdx.x;
  const int u    = tid & 255;
  const int half = tid >> 8;

  const uint4* WR = (const uint4*)(ws + WHH_OFF);     // rr<3: reg-resident rows
  const uint4* WG = WR + 24576;                       // rr=3: g rows [2][16][256]
  const unsigned short* xp = (const unsigned short*)(ws + XG_OFF);
  _Float16* hst    = (_Float16*)(ws + HST_OFF);
  _Float16* hstate = (_Float16*)(ws + HSTATE_OFF);
  float*    cstate = (float*)(ws + CSTATE_OFF);

  extern __shared__ uint8_t smem[];
  uint4*    gw    = (uint4*)smem;                     // 512 x 16 uint4 = 128 KB
  _Float16* h_lds = (_Float16*)(smem + GW_BYTES);     // 512 B
  float*    p_i   = (float*)(smem + GW_BYTES + 512);  // 4 x 1 KB partials
  float*    p_f   = p_i + 256;
  float*    p_g   = p_f + 256;
  float*    p_o   = p_g + 256;

  // ---- one-time: load reg-resident W halves (i,f,o) ----
  h2 wi[64], wf[64], wo[64];
  #pragma unroll
  for (int q = 0; q < 16; ++q) {
    U16 a;
    a.u = WR[(size_t)((0 * 2 + half) * 16 + q) * 256 + u];
    wi[4*q+0]=a.h[0]; wi[4*q+1]=a.h[1]; wi[4*q+2]=a.h[2]; wi[4*q+3]=a.h[3];
    a.u = WR[(size_t)((1 * 2 + half) * 16 + q) * 256 + u];
    wf[4*q+0]=a.h[0]; wf[4*q+1]=a.h[1]; wf[4*q+2]=a.h[2]; wf[4*q+3]=a.h[3];
    a.u = WR[(size_t)((2 * 2 + half) * 16 + q) * 256 + u];
    wo[4*q+0]=a.h[0]; wo[4*q+1]=a.h[1]; wo[4*q+2]=a.h[2]; wo[4*q+3]=a.h[3];
  }
  // ---- one-time: stage g half-rows into LDS (XOR swizzle breaks bank aliasing) ----
  const uint4* wgp = WG + (size_t)(half * 16) * 256 + u;   // + q*256 per q
  #pragma unroll
  for (int q = 0; q < 16; ++q)
    gw[tid * 16 + (q ^ (tid & 15))] = wgp[(size_t)q * 256];

  if (tid < 32) {
    uint4 z = make_uint4(0u, 0u, 0u, 0u);
    ((uint4*)h_lds)[tid] = (t0 == 0) ? z : ((const uint4*)(hstate + (size_t)b * HH))[tid];
  }
  float c = 0.f;
  if (half == 0 && t0 != 0) c = cstate[(size_t)b * HH + u];

  const size_t xrow = (size_t)b * GG;
  HU xi, xf, xgv, xo;
  if (half == 0) {
    xi.u  = xp[xrow + u];
    xf.u  = xp[xrow + 256 + u];
    xgv.u = xp[xrow + 512 + u];
    xo.u  = xp[xrow + 768 + u];
  }
  __syncthreads();

  for (int tt = 0; tt < TC; ++tt) {
    float ai = 0.f, af = 0.f, ag = 0.f, ao = 0.f;
    const uint4* hv = ((const uint4*)h_lds) + half * 16;
    #pragma unroll
    for (int q = 0; q < 16; ++q) {
      U16 hh;  hh.u  = hv[q];                          // wave-uniform broadcast
      U16 wg_; wg_.u = gw[tid * 16 + (q ^ (tid & 15))];
      #pragma unroll
      for (int j = 0; j < 4; ++j) {
        ai = fdot2f(wi[4*q+j], hh.h[j], ai);
        af = fdot2f(wf[4*q+j], hh.h[j], af);
        ag = fdot2f(wg_.h[j],  hh.h[j], ag);
        ao = fdot2f(wo[4*q+j], hh.h[j], ao);
      }
    }
    if (half == 1) { p_i[u] = ai; p_f[u] = af; p_g[u] = ag; p_o[u] = ao; }
    __syncthreads();                                   // partials visible; h reads done
    if (half == 0) {
      float gi = sigm(ai + p_i[u] + (float)xi.h);
      float gf = sigm(af + p_f[u] + (float)xf.h);
      float gg = tanh_fast(ag + p_g[u] + (float)xgv.h);
      float go = sigm(ao + p_o[u] + (float)xo.h);
      c = gf * c + gi * gg;
      float hn = go * tanh_fast(c);
      h_lds[u] = (_Float16)hn;
      hst[((size_t)tt * BB + b) * HH + u] = (_Float16)hn;
      if (tt + 1 < TC) {
        const size_t nx = xrow + (size_t)(tt + 1) * (BB * GG);
        xi.u  = xp[nx + u];
        xf.u  = xp[nx + 256 + u];
        xgv.u = xp[nx + 512 + u];
        xo.u  = xp[nx + 768 + u];
      }
      if (t0 + tt == TT - 1) {
        const size_t tail = (size_t)TT * BB * OUTD;
        out[tail + (size_t)b * HH + u] = hn;                       // h_T
        out[tail + (size_t)BB * HH + (size_t)b * HH + u] = c;      // c_T
      }
    }
    __syncthreads();                                   // new h visible
  }

  if (tid < 32) ((uint4*)(hstate + (size_t)b * HH))[tid] = ((const uint4*)h_lds)[tid];
  if (half == 0) cstate[(size_t)b * HH + u] = c;
}

// ---------------- K3: y chunk = h_hist @ W_out^T + b_out, f32 out ----------------
__global__ void __launch_bounds__(256) k3_out(uint8_t* __restrict__ ws,
                                              const float* __restrict__ b_out,
                                              float* __restrict__ out, int t0) {
  const uint4* Wp = (const uint4*)(ws + WOUT_OFF);   // [128][32] uint4
  const _Float16* hst = (const _Float16*)(ws + HST_OFF);
  const int s = blockIdx.x >> 5;                     // col segment (8 cols)
  const int m = ((blockIdx.x & 31) << 8) + threadIdx.x;

  __shared__ uint4 wlds[256];                        // 8 rows x 32 uint4
  __shared__ float bsl[8];
  wlds[threadIdx.x] = Wp[((size_t)s << 3) * 32 + threadIdx.x];
  if (threadIdx.x < 8) bsl[threadIdx.x] = b_out[(s << 3) + threadIdx.x];
  __syncthreads();

  const uint4* xr = (const uint4*)(hst + (size_t)m * HH);
  float acc[8];
  #pragma unroll
  for (int j = 0; j < 8; ++j) acc[j] = bsl[j];
  #pragma unroll 4
  for (int q = 0; q < 32; ++q) {
    U16 hhv; hhv.u = xr[q];
    #pragma unroll
    for (int j = 0; j < 8; ++j) {
      U16 w; w.u = wlds[j * 32 + q];
      acc[j] = fdot2f(w.h[0], hhv.h[0], acc[j]);
      acc[j] = fdot2f(w.h[1], hhv.h[1], acc[j]);
      acc[j] = fdot2f(w.h[2], hhv.h[2], acc[j]);
      acc[j] = fdot2f(w.h[3], hhv.h[3], acc[j]);
    }
  }
  float* orow = out + ((size_t)t0 * BB + m) * OUTD + (s << 3);
  *(float4*)(orow)     = make_float4(acc[0], acc[1], acc[2], acc[3]);
  *(float4*)(orow + 4) = make_float4(acc[4], acc[5], acc[6], acc[7]);
}

extern "C" void kernel_launch(void* const* d_in, const int* in_sizes, int n_in,
                              void* d_out, int out_size, void* d_ws, size_t ws_size,
                              hipStream_t stream) {
  const float* input = (const float*)d_in[0];
  const float* W_ih  = (const float*)d_in[1];
  const float* W_hh  = (const float*)d_in[2];
  const float* b_ih  = (const float*)d_in[3];
  const float* b_hh  = (const float*)d_in[4];
  const float* W_out = (const float*)d_in[5];
  const float* b_out = (const float*)d_in[6];
  float*   out = (float*)d_out;
  uint8_t* ws  = (uint8_t*)d_ws;

  if (ws_size < WS_NEEDED) return;   // fail validation cleanly instead of faulting

  // allow 135.7 KB dynamic LDS for k2 (gfx950: 160 KB/CU). Host-side, idempotent,
  // not a stream op -> safe under graph capture.
  hipFuncSetAttribute((const void*)k2_recur,
                      hipFuncAttributeMaxDynamicSharedMemorySize, K2_LDS_SZ);

  hipLaunchKernelGGL(k0_pack, dim3(324), dim3(256), 0, stream,
                     W_hh, W_ih, W_out, b_ih, b_hh, ws);
  for (int ch = 0; ch < NCH; ++ch) {
    const int t0 = ch * TC;
    hipLaunchKernelGGL(k1_xgemm, dim3(512), dim3(256), 0, stream, input, ws, t0);
    hipLaunchKernelGGL(k2_recur, dim3(64),  dim3(512), K2_LDS_SZ, stream, ws, out, t0);
    hipLaunchKernelGGL(k3_out,   dim3(512), dim3(256), 0, stream, ws, b_out, out, t0);
  }
}